// Round 10
// baseline (305.866 us; speedup 1.0000x reference)
//
#include <hip/hip_runtime.h>
#include <hip/hip_bf16.h>

#define NEG_SLOPE 0.2f

typedef __attribute__((ext_vector_type(8))) short short8;   // 8 bf16 (4 VGPRs)
typedef __attribute__((ext_vector_type(4))) float f32x4;    // MFMA accumulator

__device__ __forceinline__ float bflo(unsigned u) { return __uint_as_float(u << 16); }
__device__ __forceinline__ float bfhi(unsigned u) { return __uint_as_float(u & 0xffff0000u); }
__device__ __forceinline__ unsigned pk2bf(float a, float b) {
    __hip_bfloat162 t; t.x = __float2bfloat16(a); t.y = __float2bfloat16(b);
    return *reinterpret_cast<unsigned*>(&t);
}

#define KP  136   // padded k-stride for gemm1 tiles (128+8)
#define KP2 264   // padded k-stride for gemm2 tiles (256+8)

// ============ init: hist (blocks [0,Mb)) + weight prep (rest) ============
__global__ void k_init(const int* __restrict__ ei, int E, int M, int* __restrict__ deg,
    const float* __restrict__ W1, const float* __restrict__ W2,
    __hip_bfloat16* __restrict__ W1t, __hip_bfloat16* __restrict__ W2t, int Mb)
{
    int b = blockIdx.x;
    if (b < Mb) {
        int i = b * 256 + threadIdx.x;
        if (i < M) {
            int dst = (i < E) ? ei[E + i] : (i - E);
            atomicAdd(&deg[dst], 1);
        }
    } else {
        int i = (b - Mb) * 256 + threadIdx.x;
        if (i < 256 * KP) {
            int n = i / KP, k = i % KP;
            W1t[i] = __float2bfloat16(k < 128 ? W1[k * 256 + n] : 0.f);
        } else {
            int j = i - 256 * KP;
            if (j < 64 * KP2) {
                int n = j / KP2, k = j % KP2;
                W2t[j] = __float2bfloat16(k < 256 ? W2[k * 64 + n] : 0.f);
            }
        }
    }
}

// ============ scan1: per-256-block inclusive scan -> excl + block sums ============
__global__ __launch_bounds__(256) void k_scan1(const int* __restrict__ deg, int N,
    int* __restrict__ excl, int* __restrict__ bsum)
{
    __shared__ int s[256];
    int t = threadIdx.x, i = blockIdx.x * 256 + t;
    int v = (i < N) ? deg[i] : 0;
    s[t] = v; __syncthreads();
#pragma unroll
    for (int o = 1; o < 256; o <<= 1) {
        int x = (t >= o) ? s[t - o] : 0;
        __syncthreads();
        s[t] += x;
        __syncthreads();
    }
    if (i < N) excl[i] = s[t] - v;
    if (t == 255) bsum[blockIdx.x] = s[255];
}

// ============ scan23: every block redundantly scans bsum, writes its rowptr chunk ====
__global__ __launch_bounds__(256) void k_scan23(const int* __restrict__ bsum, int NB,
    const int* __restrict__ excl, int N, int M, int* __restrict__ rowptr)
{
    __shared__ int s[256];
    int t = threadIdx.x;
    s[t] = (t < NB) ? bsum[t] : 0;
    __syncthreads();
#pragma unroll
    for (int o = 1; o < 256; o <<= 1) {
        int x = (t >= o) ? s[t - o] : 0;
        __syncthreads();
        s[t] += x;
        __syncthreads();
    }
    int off = (blockIdx.x == 0) ? 0 : s[blockIdx.x - 1];   // LDS broadcast
    int i = blockIdx.x * 256 + t;
    if (i < N) rowptr[i] = excl[i] + off;
    if (i == 0) rowptr[N] = M;
}

__global__ void k_scatter(const int* __restrict__ ei, int E, int M,
    const int* __restrict__ rowptr, int* __restrict__ cnt, int* __restrict__ csr_src)
{
    int i = blockIdx.x * blockDim.x + threadIdx.x;
    if (i >= M) return;
    int src, dst;
    if (i < E) { src = ei[i]; dst = ei[E + i]; } else { src = i - E; dst = src; }
    int pos = rowptr[dst] + atomicAdd(&cnt[dst], 1);
    csr_src[pos] = src;
}

// ============ Layer 1 GEMM via MFMA + fused att dots ============
// Block: 64 rows x 128 cols (blockIdx.y = col half -> heads {2y, 2y+1}).
// Epilogue: acc -> LDS tile (reuse sA) -> coalesced uint4 stores.
__global__ __launch_bounds__(256) void k_gemm1_mfma(
    const float* __restrict__ x, const __hip_bfloat16* __restrict__ W1t,
    const float* __restrict__ as1, const float* __restrict__ ad1,
    __hip_bfloat16* __restrict__ h1b, float* __restrict__ a_s1, float* __restrict__ a_d1,
    int N)
{
    const int n0 = blockIdx.x * 64;
    const int c0 = blockIdx.y * 128;
    const int t = threadIdx.x, wv = t >> 6, lane = t & 63;
    const int l15 = lane & 15, q = lane >> 4;

    __shared__ short sA[64 * KP];    // staging A; later reused as output tile
    __shared__ short sB[128 * KP];

    {
        const float4* x4 = (const float4*)x;
        for (int i = t; i < 2048; i += 256) {
            int row = i >> 5, kq = i & 31;
            float4 v = make_float4(0.f, 0.f, 0.f, 0.f);
            if (n0 + row < N) v = x4[(size_t)(n0 + row) * 32 + kq];
            uint2 p; p.x = pk2bf(v.x, v.y); p.y = pk2bf(v.z, v.w);
            *(uint2*)(sA + row * KP + kq * 4) = p;
        }
    }
    {
        const uint4* src = (const uint4*)((const short*)W1t + (size_t)c0 * KP);
        uint4* dst = (uint4*)sB;
        for (int i = t; i < (128 * KP * 2) / 16; i += 256) dst[i] = src[i];
    }
    __syncthreads();

    short8 af[4];
#pragma unroll
    for (int kc = 0; kc < 4; ++kc)
        af[kc] = *(const short8*)(sA + (wv * 16 + l15) * KP + kc * 32 + q * 8);

    f32x4 acc[8];
#pragma unroll
    for (int nt = 0; nt < 8; ++nt) {
        f32x4 a = {0.f, 0.f, 0.f, 0.f};
#pragma unroll
        for (int kc = 0; kc < 4; ++kc) {
            short8 bf = *(const short8*)(sB + (nt * 16 + l15) * KP + kc * 32 + q * 8);
            a = __builtin_amdgcn_mfma_f32_16x16x32_bf16(af[kc], bf, a, 0, 0, 0);
        }
        acc[nt] = a;
    }

    // ---- epilogue: transpose through LDS for coalesced h1b stores ----
    __syncthreads();                         // all sA reads done; safe to overwrite
#pragma unroll
    for (int nt = 0; nt < 8; ++nt) {
#pragma unroll
        for (int r = 0; r < 4; ++r) {
            int row = wv * 16 + q * 4 + r;                // 0..63 (block-local)
            sA[row * KP + nt * 16 + l15] = (short)__bfloat16_as_ushort(__float2bfloat16(acc[nt][r]));
        }
    }
    __syncthreads();
    // 64 rows x 128 cols bf16 = 1024 uint4; 4 iterations of 256 threads
#pragma unroll
    for (int k = 0; k < 4; ++k) {
        int i = t + k * 256;
        int row = i >> 4, off = i & 15;                   // 16 uint4 per row
        if (n0 + row < N) {
            uint4 v = *(const uint4*)(sA + row * KP + off * 8);
            *(uint4*)(h1b + (size_t)(n0 + row) * 256 + c0 + off * 8) = v;
        }
    }

    // ---- fused attention dots for heads {2y, 2y+1} ----
    float asv[8], adv[8];
#pragma unroll
    for (int nt = 0; nt < 8; ++nt) {
        asv[nt] = as1[c0 + nt * 16 + l15];
        adv[nt] = ad1[c0 + nt * 16 + l15];
    }
    const int hb = blockIdx.y * 2;
#pragma unroll
    for (int r = 0; r < 4; ++r) {
        float slo = 0.f, shi = 0.f, dlo = 0.f, dhi = 0.f;
#pragma unroll
        for (int nt = 0; nt < 4; ++nt) { slo += acc[nt][r] * asv[nt]; dlo += acc[nt][r] * adv[nt]; }
#pragma unroll
        for (int nt = 4; nt < 8; ++nt) { shi += acc[nt][r] * asv[nt]; dhi += acc[nt][r] * adv[nt]; }
#pragma unroll
        for (int o = 1; o < 16; o <<= 1) {
            slo += __shfl_xor(slo, o); shi += __shfl_xor(shi, o);
            dlo += __shfl_xor(dlo, o); dhi += __shfl_xor(dhi, o);
        }
        int row = n0 + wv * 16 + q * 4 + r;
        if (l15 == 0 && row < N) {
            a_s1[row * 4 + hb]     = slo; a_s1[row * 4 + hb + 1] = shi;
            a_d1[row * 4 + hb]     = dlo; a_d1[row * 4 + hb + 1] = dhi;
        }
    }
}

// ============ Layer 1 fused softmax+aggregate+bias+ELU ============
// 1 wave per dst (no barriers). Lane t: cols {4t..4t+3}; head h=t>>4.
// 16 gathers in flight; byte offsets precomputed in LDS.
__global__ __launch_bounds__(64) void k_agg1_fused(const int* __restrict__ rowptr,
    const int* __restrict__ csr_src, const float* __restrict__ a_s1,
    const float* __restrict__ a_d1, const __hip_bfloat16* __restrict__ h1b,
    const float* __restrict__ b1, __hip_bfloat16* __restrict__ h2b)
{
    const int dst = blockIdx.x, t = threadIdx.x;
    const int h = t >> 4;
    const int start = rowptr[dst], end = rowptr[dst + 1];
    __shared__ int   s_off[64];
    __shared__ float s_ex[64][4];
    const char* hbase = (const char*)h1b;
    float4 ad = ((const float4*)a_d1)[dst];
    float d0 = 0.f, d1 = 0.f, d2 = 0.f, d3 = 0.f;
    float a0 = 0.f, a1 = 0.f, a2 = 0.f, a3 = 0.f;

    for (int base = start; base < end; base += 64) {
        int nloc = end - base; if (nloc > 64) nloc = 64;
        if (t < nloc) {
            int src = csr_src[base + t];
            s_off[t] = src << 9;                         // byte offset src*512
            float4 as = ((const float4*)a_s1)[src];
            float e0 = as.x + ad.x; e0 = e0 > 0.f ? e0 : NEG_SLOPE * e0;
            float e1 = as.y + ad.y; e1 = e1 > 0.f ? e1 : NEG_SLOPE * e1;
            float e2 = as.z + ad.z; e2 = e2 > 0.f ? e2 : NEG_SLOPE * e2;
            float e3 = as.w + ad.w; e3 = e3 > 0.f ? e3 : NEG_SLOPE * e3;
            float x0 = __expf(e0), x1 = __expf(e1), x2 = __expf(e2), x3 = __expf(e3);
            s_ex[t][0] = x0; s_ex[t][1] = x1; s_ex[t][2] = x2; s_ex[t][3] = x3;
            d0 += x0; d1 += x1; d2 += x2; d3 += x3;
        }
        int j = 0;
        for (; j + 15 < nloc; j += 16) {
            uint2 v[16];
#pragma unroll
            for (int q = 0; q < 16; ++q)
                v[q] = *(const uint2*)(hbase + (size_t)(unsigned)s_off[j + q] + t * 8);
#pragma unroll
            for (int q = 0; q < 16; ++q) {
                float e = s_ex[j + q][h];
                a0 += e * bflo(v[q].x); a1 += e * bfhi(v[q].x);
                a2 += e * bflo(v[q].y); a3 += e * bfhi(v[q].y);
            }
        }
        for (; j + 7 < nloc; j += 8) {
            uint2 v[8];
#pragma unroll
            for (int q = 0; q < 8; ++q)
                v[q] = *(const uint2*)(hbase + (size_t)(unsigned)s_off[j + q] + t * 8);
#pragma unroll
            for (int q = 0; q < 8; ++q) {
                float e = s_ex[j + q][h];
                a0 += e * bflo(v[q].x); a1 += e * bfhi(v[q].x);
                a2 += e * bflo(v[q].y); a3 += e * bfhi(v[q].y);
            }
        }
        for (; j < nloc; ++j) {
            uint2 v = *(const uint2*)(hbase + (size_t)(unsigned)s_off[j] + t * 8);
            float e = s_ex[j][h];
            a0 += e * bflo(v.x); a1 += e * bfhi(v.x);
            a2 += e * bflo(v.y); a3 += e * bfhi(v.y);
        }
    }
#pragma unroll
    for (int o = 32; o > 0; o >>= 1) {
        d0 += __shfl_xor(d0, o); d1 += __shfl_xor(d1, o);
        d2 += __shfl_xor(d2, o); d3 += __shfl_xor(d3, o);
    }
    float den = (h == 0) ? d0 : (h == 1) ? d1 : (h == 2) ? d2 : d3;
    float inv = 1.0f / den;
    float4 bb = ((const float4*)b1)[t];
    float v0 = a0 * inv + bb.x; v0 = v0 > 0.f ? v0 : (__expf(v0) - 1.f);
    float v1 = a1 * inv + bb.y; v1 = v1 > 0.f ? v1 : (__expf(v1) - 1.f);
    float v2 = a2 * inv + bb.z; v2 = v2 > 0.f ? v2 : (__expf(v2) - 1.f);
    float v3 = a3 * inv + bb.w; v3 = v3 > 0.f ? v3 : (__expf(v3) - 1.f);
    __hip_bfloat162 p0, p1;
    p0.x = __float2bfloat16(v0); p0.y = __float2bfloat16(v1);
    p1.x = __float2bfloat16(v2); p1.y = __float2bfloat16(v3);
    __hip_bfloat162* op = (__hip_bfloat162*)(h2b + (size_t)dst * 256);
    op[2 * t] = p0; op[2 * t + 1] = p1;
}

// ============ Layer 2 GEMM via MFMA + fused att dots ============
// Block: 32 rows x 64 cols. Epilogue: LDS transpose -> coalesced stores.
__global__ __launch_bounds__(256) void k_gemm2_mfma(
    const __hip_bfloat16* __restrict__ h2b, const __hip_bfloat16* __restrict__ W2t,
    const float* __restrict__ as2, const float* __restrict__ ad2,
    __hip_bfloat16* __restrict__ h3b, float* __restrict__ a_s2, float* __restrict__ a_d2,
    int N)
{
    const int n0 = blockIdx.x * 32;
    const int t = threadIdx.x, wv = t >> 6, lane = t & 63;
    const int l15 = lane & 15, q = lane >> 4;
    const int rs = wv & 1, ch = wv >> 1;

    __shared__ short sA[32 * KP2];   // staging A; later reused as output tile
    __shared__ short sB[64 * KP2];

    {
        const uint4* src = (const uint4*)W2t;
        uint4* dst = (uint4*)sB;
        for (int i = t; i < (64 * KP2 * 2) / 16; i += 256) dst[i] = src[i];
    }
    {
        for (int i = t; i < 1024; i += 256) {
            int row = i >> 5, kq = i & 31;
            uint4 v = make_uint4(0, 0, 0, 0);
            if (n0 + row < N) v = ((const uint4*)(h2b + (size_t)(n0 + row) * 256))[kq];
            *(uint4*)(sA + row * KP2 + kq * 8) = v;
        }
    }
    __syncthreads();

    short8 af[8];
#pragma unroll
    for (int kc = 0; kc < 8; ++kc)
        af[kc] = *(const short8*)(sA + (rs * 16 + l15) * KP2 + kc * 32 + q * 8);

    f32x4 acc[2];
#pragma unroll
    for (int nt = 0; nt < 2; ++nt) {
        f32x4 a = {0.f, 0.f, 0.f, 0.f};
#pragma unroll
        for (int kc = 0; kc < 8; ++kc) {
            short8 bf = *(const short8*)(sB + (ch * 32 + nt * 16 + l15) * KP2 + kc * 32 + q * 8);
            a = __builtin_amdgcn_mfma_f32_16x16x32_bf16(af[kc], bf, a, 0, 0, 0);
        }
        acc[nt] = a;
    }

    // ---- epilogue: transpose through LDS (tile 32 x 64, stride 72) ----
    __syncthreads();
#pragma unroll
    for (int nt = 0; nt < 2; ++nt) {
#pragma unroll
        for (int r = 0; r < 4; ++r) {
            int row = rs * 16 + q * 4 + r;               // 0..31
            sA[row * 72 + ch * 32 + nt * 16 + l15] =
                (short)__bfloat16_as_ushort(__float2bfloat16(acc[nt][r]));
        }
    }
    __syncthreads();
    {   // 32 rows x 64 cols bf16 = 256 uint4; one iteration
        int row = t >> 3, off = t & 7;
        if (n0 + row < N) {
            uint4 v = *(const uint4*)(sA + row * 72 + off * 8);
            *(uint4*)(h3b + (size_t)(n0 + row) * 64 + off * 8) = v;
        }
    }

    float asv[2], adv[2];
#pragma unroll
    for (int nt = 0; nt < 2; ++nt) {
        int col = ch * 32 + nt * 16 + l15;
        asv[nt] = as2[col]; adv[nt] = ad2[col];
    }
#pragma unroll
    for (int r = 0; r < 4; ++r) {
        int row = n0 + rs * 16 + q * 4 + r;
        float s = acc[0][r] * asv[0] + acc[1][r] * asv[1];
        float d = acc[0][r] * adv[0] + acc[1][r] * adv[1];
#pragma unroll
        for (int o = 1; o < 16; o <<= 1) { s += __shfl_xor(s, o); d += __shfl_xor(d, o); }
        if (l15 == 0 && row < N) {
            atomicAdd(&a_s2[row], s);
            atomicAdd(&a_d2[row], d);
        }
    }
}

// ============ Layer 2 fused softmax+aggregate + b2 -> out ============
// 8 dsts/block (4 waves x two 32-lane halves), no barriers, 16-deep ILP.
__global__ __launch_bounds__(256) void k_agg2_fused(const int* __restrict__ rowptr,
    const int* __restrict__ csr_src, const float* __restrict__ a_s2,
    const float* __restrict__ a_d2, const __hip_bfloat16* __restrict__ h3b,
    const float* __restrict__ b2, float* __restrict__ out, int N)
{
    const int tt = threadIdx.x, wv = tt >> 6, t = tt & 63;
    const int half = t >> 5, l = t & 31;
    const int dst = blockIdx.x * 8 + wv * 2 + half;
    const bool valid = dst < N;
    __shared__ int   s_off[4][2][32];
    __shared__ float s_ex[4][2][32];
    int start = 0, end = 0;
    float adv = 0.f;
    if (valid) { start = rowptr[dst]; end = rowptr[dst + 1]; adv = a_d2[dst]; }
    int trips = (end - start + 31) >> 5;
#pragma unroll
    for (int o = 32; o > 0; o >>= 1) { int u = __shfl_xor(trips, o); trips = u > trips ? u : trips; }
    const char* hbase = (const char*)h3b;
    float den = 0.f, acc0 = 0.f, acc1 = 0.f;

    for (int it = 0; it < trips; ++it) {
        int base = start + it * 32;
        int nloc = end - base; if (nloc > 32) nloc = 32; if (nloc < 0) nloc = 0;
        if (l < nloc) {
            int src = csr_src[base + l];
            s_off[wv][half][l] = src << 7;               // byte offset src*128
            float e = a_s2[src] + adv;
            e = e > 0.f ? e : NEG_SLOPE * e;
            float ex = __expf(e);
            s_ex[wv][half][l] = ex;
            den += ex;
        }
        int j = 0;
        for (; j + 15 < nloc; j += 16) {
            unsigned v[16];
#pragma unroll
            for (int q = 0; q < 16; ++q)
                v[q] = *(const unsigned*)(hbase + (size_t)(unsigned)s_off[wv][half][j + q] + l * 4);
#pragma unroll
            for (int q = 0; q < 16; ++q) {
                float e = s_ex[wv][half][j + q];
                acc0 += e * bflo(v[q]); acc1 += e * bfhi(v[q]);
            }
        }
        for (; j + 7 < nloc; j += 8) {
            unsigned v[8];
#pragma unroll
            for (int q = 0; q < 8; ++q)
                v[q] = *(const unsigned*)(hbase + (size_t)(unsigned)s_off[wv][half][j + q] + l * 4);
#pragma unroll
            for (int q = 0; q < 8; ++q) {
                float e = s_ex[wv][half][j + q];
                acc0 += e * bflo(v[q]); acc1 += e * bfhi(v[q]);
            }
        }
        for (; j < nloc; ++j) {
            unsigned v = *(const unsigned*)(hbase + (size_t)(unsigned)s_off[wv][half][j] + l * 4);
            float e = s_ex[wv][half][j];
            acc0 += e * bflo(v); acc1 += e * bfhi(v);
        }
    }
#pragma unroll
    for (int o = 16; o > 0; o >>= 1) den += __shfl_xor(den, o);
    if (valid) {
        float inv = 1.0f / den;
        float2 bb = ((const float2*)b2)[l];
        float2 ov; ov.x = acc0 * inv + bb.x; ov.y = acc1 * inv + bb.y;
        ((float2*)(out + (size_t)dst * 64))[l] = ov;
    }
}

extern "C" void kernel_launch(void* const* d_in, const int* in_sizes, int n_in,
                              void* d_out, int out_size, void* d_ws, size_t ws_size,
                              hipStream_t stream)
{
    const float* x   = (const float*)d_in[0];
    const int*   ei  = (const int*)d_in[1];
    const float* W1  = (const float*)d_in[2];
    const float* as1 = (const float*)d_in[3];
    const float* ad1 = (const float*)d_in[4];
    const float* b1  = (const float*)d_in[5];
    const float* W2  = (const float*)d_in[6];
    const float* as2 = (const float*)d_in[7];
    const float* ad2 = (const float*)d_in[8];
    const float* b2  = (const float*)d_in[9];
    float* out = (float*)d_out;

    const int N = in_sizes[0] / 128;      // 50000
    const int E = in_sizes[1] / 2;        // 800000
    const int M = E + N;                  // edges + self loops
    const int NB = (N + 255) / 256;       // scan blocks (196 <= 256)
    const int Mb = (M + 255) / 256;

    // ---- workspace layout (256B-aligned) ----
    char* w = (char*)d_ws;
    size_t o = 0;
    auto alloc = [&](size_t bytes) { size_t r = o; o = (o + bytes + 255) & ~(size_t)255; return r; };
    __hip_bfloat16* h1b   = (__hip_bfloat16*)(w + alloc((size_t)N * 256 * 2)); // 25.6 MB
    float* a_s1           = (float*)(w + alloc((size_t)N * 4 * 4));
    float* a_d1           = (float*)(w + alloc((size_t)N * 4 * 4));
    __hip_bfloat16* h2b   = (__hip_bfloat16*)(w + alloc((size_t)N * 256 * 2)); // 25.6 MB
    __hip_bfloat16* h3b   = (__hip_bfloat16*)(w + alloc((size_t)N * 64 * 2));  // 6.4 MB
    // zero-block: a_s2 | a_d2 | deg | cnt — one memset covers the span
    size_t z0 = o;
    float* a_s2           = (float*)(w + alloc((size_t)N * 4));
    float* a_d2           = (float*)(w + alloc((size_t)N * 4));
    int* deg              = (int*)(w + alloc((size_t)N * 4));
    int* cnt              = (int*)(w + alloc((size_t)N * 4));
    size_t z1 = o;
    int* rowptr           = (int*)(w + alloc((size_t)(N + 1) * 4));
    int* excl             = (int*)(w + alloc((size_t)N * 4));
    int* bsum             = (int*)(w + alloc((size_t)NB * 4));
    int* csr_src          = (int*)(w + alloc((size_t)M * 4));                  // 3.4 MB
    __hip_bfloat16* W1t   = (__hip_bfloat16*)(w + alloc((size_t)256 * KP * 2));
    __hip_bfloat16* W2t   = (__hip_bfloat16*)(w + alloc((size_t)64 * KP2 * 2));

    // ---- zero + init (hist + weight prep fused) ----
    hipMemsetAsync(w + z0, 0, z1 - z0, stream);
    const int Pb = (256 * KP + 64 * KP2 + 255) / 256;
    k_init<<<Mb + Pb, 256, 0, stream>>>(ei, E, M, deg, W1, W2, W1t, W2t, Mb);

    // ---- CSR offsets + scatter ----
    k_scan1<<<NB, 256, 0, stream>>>(deg, N, excl, bsum);
    k_scan23<<<NB, 256, 0, stream>>>(bsum, NB, excl, N, M, rowptr);
    k_scatter<<<Mb, 256, 0, stream>>>(ei, E, M, rowptr, cnt, csr_src);

    // ---- layer 1 ----
    k_gemm1_mfma<<<dim3((N + 63) / 64, 2), 256, 0, stream>>>(x, W1t, as1, ad1, h1b, a_s1, a_d1, N);
    k_agg1_fused<<<N, 64, 0, stream>>>(rowptr, csr_src, a_s1, a_d1, h1b, b1, h2b);

    // ---- layer 2 ----
    k_gemm2_mfma<<<(N + 31) / 32, 256, 0, stream>>>(h2b, W2t, as2, ad2, h3b, a_s2, a_d2, N);
    k_agg2_fused<<<(N + 7) / 8, 256, 0, stream>>>(rowptr, csr_src, a_s2, a_d2, h3b, b2, out, N);
}

// Round 11
// 301.874 us; speedup vs baseline: 1.0132x; 1.0132x over previous
//
#include <hip/hip_runtime.h>
#include <hip/hip_bf16.h>

#define NEG_SLOPE 0.2f

typedef __attribute__((ext_vector_type(8))) short short8;   // 8 bf16 (4 VGPRs)
typedef __attribute__((ext_vector_type(4))) float f32x4;    // MFMA accumulator

__device__ __forceinline__ float bflo(unsigned u) { return __uint_as_float(u << 16); }
__device__ __forceinline__ float bfhi(unsigned u) { return __uint_as_float(u & 0xffff0000u); }
__device__ __forceinline__ unsigned pk2bf(float a, float b) {
    __hip_bfloat162 t; t.x = __float2bfloat16(a); t.y = __float2bfloat16(b);
    return *reinterpret_cast<unsigned*>(&t);
}

#define KP  136   // padded k-stride for gemm1 tiles (128+8)
#define KP2 264   // padded k-stride for gemm2 tiles (256+8)

// ============ init: hist (blocks [0,Mb)) + weight prep (rest) ============
__global__ void k_init(const int* __restrict__ ei, int E, int M, int* __restrict__ deg,
    const float* __restrict__ W1, const float* __restrict__ W2,
    __hip_bfloat16* __restrict__ W1t, __hip_bfloat16* __restrict__ W2t, int Mb)
{
    int b = blockIdx.x;
    if (b < Mb) {
        int i = b * 256 + threadIdx.x;
        if (i < M) {
            int dst = (i < E) ? ei[E + i] : (i - E);
            atomicAdd(&deg[dst], 1);
        }
    } else {
        int i = (b - Mb) * 256 + threadIdx.x;
        if (i < 256 * KP) {
            int n = i / KP, k = i % KP;
            W1t[i] = __float2bfloat16(k < 128 ? W1[k * 256 + n] : 0.f);
        } else {
            int j = i - 256 * KP;
            if (j < 64 * KP2) {
                int n = j / KP2, k = j % KP2;
                W2t[j] = __float2bfloat16(k < 256 ? W2[k * 64 + n] : 0.f);
            }
        }
    }
}

// ============ scan23: every block redundantly scans bsum, writes its rowptr chunk ====
__global__ __launch_bounds__(256) void k_scan23(const int* __restrict__ bsum, int NB,
    const int* __restrict__ excl, int N, int M, int* __restrict__ rowptr)
{
    __shared__ int s[256];
    int t = threadIdx.x;
    s[t] = (t < NB) ? bsum[t] : 0;
    __syncthreads();
#pragma unroll
    for (int o = 1; o < 256; o <<= 1) {
        int x = (t >= o) ? s[t - o] : 0;
        __syncthreads();
        s[t] += x;
        __syncthreads();
    }
    int off = (blockIdx.x == 0) ? 0 : s[blockIdx.x - 1];   // LDS broadcast
    int i = blockIdx.x * 256 + t;
    if (i < N) rowptr[i] = excl[i] + off;
    if (i == 0) rowptr[N] = M;
}

__global__ void k_scatter(const int* __restrict__ ei, int E, int M,
    const int* __restrict__ rowptr, int* __restrict__ cnt, int* __restrict__ csr_src)
{
    int i = blockIdx.x * blockDim.x + threadIdx.x;
    if (i >= M) return;
    int src, dst;
    if (i < E) { src = ei[i]; dst = ei[E + i]; } else { src = i - E; dst = src; }
    int pos = rowptr[dst] + atomicAdd(&cnt[dst], 1);
    csr_src[pos] = src;
}

// ============ Layer 1 GEMM via MFMA + fused att dots + piggybacked scan1 ============
// Block: 64 rows x 128 cols (blockIdx.y = col half -> heads {2y, 2y+1}).
// Blocks with blockIdx.x >= G1x run the scan1 pass instead (independent work
// that would otherwise serialize on the stream; deg is complete after k_init).
__global__ __launch_bounds__(256) void k_gemm1_mfma(
    const float* __restrict__ x, const __hip_bfloat16* __restrict__ W1t,
    const float* __restrict__ as1, const float* __restrict__ ad1,
    __hip_bfloat16* __restrict__ h1b, float* __restrict__ a_s1, float* __restrict__ a_d1,
    int N, const int* __restrict__ deg, int* __restrict__ excl, int* __restrict__ bsum,
    int NB, int G1x)
{
    __shared__ short sA[64 * KP];
    __shared__ short sB[128 * KP];

    if (blockIdx.x >= G1x) {
        // ---- scan1 block: per-256 inclusive scan of deg -> excl + bsum ----
        int sb = (blockIdx.x - G1x) * 2 + blockIdx.y;
        if (sb >= NB) return;
        int* s = (int*)sA;
        int t = threadIdx.x, i = sb * 256 + t;
        int v = (i < N) ? deg[i] : 0;
        s[t] = v; __syncthreads();
#pragma unroll
        for (int o = 1; o < 256; o <<= 1) {
            int y = (t >= o) ? s[t - o] : 0;
            __syncthreads();
            s[t] += y;
            __syncthreads();
        }
        if (i < N) excl[i] = s[t] - v;
        if (t == 255) bsum[sb] = s[255];
        return;
    }

    const int n0 = blockIdx.x * 64;
    const int c0 = blockIdx.y * 128;
    const int t = threadIdx.x, wv = t >> 6, lane = t & 63;
    const int l15 = lane & 15, q = lane >> 4;

    {
        const float4* x4 = (const float4*)x;
        for (int i = t; i < 2048; i += 256) {
            int row = i >> 5, kq = i & 31;
            float4 v = make_float4(0.f, 0.f, 0.f, 0.f);
            if (n0 + row < N) v = x4[(size_t)(n0 + row) * 32 + kq];
            uint2 p; p.x = pk2bf(v.x, v.y); p.y = pk2bf(v.z, v.w);
            *(uint2*)(sA + row * KP + kq * 4) = p;
        }
    }
    {
        const uint4* src = (const uint4*)((const short*)W1t + (size_t)c0 * KP);
        uint4* dst = (uint4*)sB;
        for (int i = t; i < (128 * KP * 2) / 16; i += 256) dst[i] = src[i];
    }
    __syncthreads();

    short8 af[4];
#pragma unroll
    for (int kc = 0; kc < 4; ++kc)
        af[kc] = *(const short8*)(sA + (wv * 16 + l15) * KP + kc * 32 + q * 8);

    f32x4 acc[8];
#pragma unroll
    for (int nt = 0; nt < 8; ++nt) {
        f32x4 a = {0.f, 0.f, 0.f, 0.f};
#pragma unroll
        for (int kc = 0; kc < 4; ++kc) {
            short8 bf = *(const short8*)(sB + (nt * 16 + l15) * KP + kc * 32 + q * 8);
            a = __builtin_amdgcn_mfma_f32_16x16x32_bf16(af[kc], bf, a, 0, 0, 0);
        }
        acc[nt] = a;
    }

    // epilogue: direct stores (round-8 form; LDS-transpose variant measured slower)
#pragma unroll
    for (int nt = 0; nt < 8; ++nt) {
#pragma unroll
        for (int r = 0; r < 4; ++r) {
            int row = n0 + wv * 16 + q * 4 + r;
            if (row < N)
                h1b[(size_t)row * 256 + c0 + nt * 16 + l15] = __float2bfloat16(acc[nt][r]);
        }
    }

    // fused attention dots for heads {2y, 2y+1}
    float asv[8], adv[8];
#pragma unroll
    for (int nt = 0; nt < 8; ++nt) {
        asv[nt] = as1[c0 + nt * 16 + l15];
        adv[nt] = ad1[c0 + nt * 16 + l15];
    }
    const int hb = blockIdx.y * 2;
#pragma unroll
    for (int r = 0; r < 4; ++r) {
        float slo = 0.f, shi = 0.f, dlo = 0.f, dhi = 0.f;
#pragma unroll
        for (int nt = 0; nt < 4; ++nt) { slo += acc[nt][r] * asv[nt]; dlo += acc[nt][r] * adv[nt]; }
#pragma unroll
        for (int nt = 4; nt < 8; ++nt) { shi += acc[nt][r] * asv[nt]; dhi += acc[nt][r] * adv[nt]; }
#pragma unroll
        for (int o = 1; o < 16; o <<= 1) {
            slo += __shfl_xor(slo, o); shi += __shfl_xor(shi, o);
            dlo += __shfl_xor(dlo, o); dhi += __shfl_xor(dhi, o);
        }
        int row = n0 + wv * 16 + q * 4 + r;
        if (l15 == 0 && row < N) {
            a_s1[row * 4 + hb]     = slo; a_s1[row * 4 + hb + 1] = shi;
            a_d1[row * 4 + hb]     = dlo; a_d1[row * 4 + hb + 1] = dhi;
        }
    }
}

// ============ Layer 1 fused softmax+aggregate+bias+ELU ============
// 1 wave per dst (no barriers). Lane t: cols {4t..4t+3}; head h=t>>4.
// 16 gathers in flight; byte offsets precomputed in LDS.
__global__ __launch_bounds__(64) void k_agg1_fused(const int* __restrict__ rowptr,
    const int* __restrict__ csr_src, const float* __restrict__ a_s1,
    const float* __restrict__ a_d1, const __hip_bfloat16* __restrict__ h1b,
    const float* __restrict__ b1, __hip_bfloat16* __restrict__ h2b)
{
    const int dst = blockIdx.x, t = threadIdx.x;
    const int h = t >> 4;
    const int start = rowptr[dst], end = rowptr[dst + 1];
    __shared__ int   s_off[64];
    __shared__ float s_ex[64][4];
    const char* hbase = (const char*)h1b;
    float4 ad = ((const float4*)a_d1)[dst];
    float d0 = 0.f, d1 = 0.f, d2 = 0.f, d3 = 0.f;
    float a0 = 0.f, a1 = 0.f, a2 = 0.f, a3 = 0.f;

    for (int base = start; base < end; base += 64) {
        int nloc = end - base; if (nloc > 64) nloc = 64;
        if (t < nloc) {
            int src = csr_src[base + t];
            s_off[t] = src << 9;                         // byte offset src*512
            float4 as = ((const float4*)a_s1)[src];
            float e0 = as.x + ad.x; e0 = e0 > 0.f ? e0 : NEG_SLOPE * e0;
            float e1 = as.y + ad.y; e1 = e1 > 0.f ? e1 : NEG_SLOPE * e1;
            float e2 = as.z + ad.z; e2 = e2 > 0.f ? e2 : NEG_SLOPE * e2;
            float e3 = as.w + ad.w; e3 = e3 > 0.f ? e3 : NEG_SLOPE * e3;
            float x0 = __expf(e0), x1 = __expf(e1), x2 = __expf(e2), x3 = __expf(e3);
            s_ex[t][0] = x0; s_ex[t][1] = x1; s_ex[t][2] = x2; s_ex[t][3] = x3;
            d0 += x0; d1 += x1; d2 += x2; d3 += x3;
        }
        int j = 0;
        for (; j + 15 < nloc; j += 16) {
            uint2 v[16];
#pragma unroll
            for (int q = 0; q < 16; ++q)
                v[q] = *(const uint2*)(hbase + (size_t)(unsigned)s_off[j + q] + t * 8);
#pragma unroll
            for (int q = 0; q < 16; ++q) {
                float e = s_ex[j + q][h];
                a0 += e * bflo(v[q].x); a1 += e * bfhi(v[q].x);
                a2 += e * bflo(v[q].y); a3 += e * bfhi(v[q].y);
            }
        }
        for (; j + 7 < nloc; j += 8) {
            uint2 v[8];
#pragma unroll
            for (int q = 0; q < 8; ++q)
                v[q] = *(const uint2*)(hbase + (size_t)(unsigned)s_off[j + q] + t * 8);
#pragma unroll
            for (int q = 0; q < 8; ++q) {
                float e = s_ex[j + q][h];
                a0 += e * bflo(v[q].x); a1 += e * bfhi(v[q].x);
                a2 += e * bflo(v[q].y); a3 += e * bfhi(v[q].y);
            }
        }
        for (; j < nloc; ++j) {
            uint2 v = *(const uint2*)(hbase + (size_t)(unsigned)s_off[j] + t * 8);
            float e = s_ex[j][h];
            a0 += e * bflo(v.x); a1 += e * bfhi(v.x);
            a2 += e * bflo(v.y); a3 += e * bfhi(v.y);
        }
    }
#pragma unroll
    for (int o = 32; o > 0; o >>= 1) {
        d0 += __shfl_xor(d0, o); d1 += __shfl_xor(d1, o);
        d2 += __shfl_xor(d2, o); d3 += __shfl_xor(d3, o);
    }
    float den = (h == 0) ? d0 : (h == 1) ? d1 : (h == 2) ? d2 : d3;
    float inv = 1.0f / den;
    float4 bb = ((const float4*)b1)[t];
    float v0 = a0 * inv + bb.x; v0 = v0 > 0.f ? v0 : (__expf(v0) - 1.f);
    float v1 = a1 * inv + bb.y; v1 = v1 > 0.f ? v1 : (__expf(v1) - 1.f);
    float v2 = a2 * inv + bb.z; v2 = v2 > 0.f ? v2 : (__expf(v2) - 1.f);
    float v3 = a3 * inv + bb.w; v3 = v3 > 0.f ? v3 : (__expf(v3) - 1.f);
    __hip_bfloat162 p0, p1;
    p0.x = __float2bfloat16(v0); p0.y = __float2bfloat16(v1);
    p1.x = __float2bfloat16(v2); p1.y = __float2bfloat16(v3);
    __hip_bfloat162* op = (__hip_bfloat162*)(h2b + (size_t)dst * 256);
    op[2 * t] = p0; op[2 * t + 1] = p1;
}

// ============ Layer 2 GEMM via MFMA + fused att dots (direct stores) ============
__global__ __launch_bounds__(256) void k_gemm2_mfma(
    const __hip_bfloat16* __restrict__ h2b, const __hip_bfloat16* __restrict__ W2t,
    const float* __restrict__ as2, const float* __restrict__ ad2,
    __hip_bfloat16* __restrict__ h3b, float* __restrict__ a_s2, float* __restrict__ a_d2,
    int N)
{
    const int n0 = blockIdx.x * 32;
    const int t = threadIdx.x, wv = t >> 6, lane = t & 63;
    const int l15 = lane & 15, q = lane >> 4;
    const int rs = wv & 1, ch = wv >> 1;

    __shared__ short sA[32 * KP2];
    __shared__ short sB[64 * KP2];

    {
        const uint4* src = (const uint4*)W2t;
        uint4* dst = (uint4*)sB;
        for (int i = t; i < (64 * KP2 * 2) / 16; i += 256) dst[i] = src[i];
    }
    {
        for (int i = t; i < 1024; i += 256) {
            int row = i >> 5, kq = i & 31;
            uint4 v = make_uint4(0, 0, 0, 0);
            if (n0 + row < N) v = ((const uint4*)(h2b + (size_t)(n0 + row) * 256))[kq];
            *(uint4*)(sA + row * KP2 + kq * 8) = v;
        }
    }
    __syncthreads();

    short8 af[8];
#pragma unroll
    for (int kc = 0; kc < 8; ++kc)
        af[kc] = *(const short8*)(sA + (rs * 16 + l15) * KP2 + kc * 32 + q * 8);

    f32x4 acc[2];
#pragma unroll
    for (int nt = 0; nt < 2; ++nt) {
        f32x4 a = {0.f, 0.f, 0.f, 0.f};
#pragma unroll
        for (int kc = 0; kc < 8; ++kc) {
            short8 bf = *(const short8*)(sB + (ch * 32 + nt * 16 + l15) * KP2 + kc * 32 + q * 8);
            a = __builtin_amdgcn_mfma_f32_16x16x32_bf16(af[kc], bf, a, 0, 0, 0);
        }
        acc[nt] = a;
    }

    float asv[2], adv[2];
#pragma unroll
    for (int nt = 0; nt < 2; ++nt) {
        int col = ch * 32 + nt * 16 + l15;
        asv[nt] = as2[col]; adv[nt] = ad2[col];
    }
#pragma unroll
    for (int r = 0; r < 4; ++r) {
        int row = n0 + rs * 16 + q * 4 + r;
        if (row < N) {
#pragma unroll
            for (int nt = 0; nt < 2; ++nt)
                h3b[(size_t)row * 64 + ch * 32 + nt * 16 + l15] = __float2bfloat16(acc[nt][r]);
        }
        float s = acc[0][r] * asv[0] + acc[1][r] * asv[1];
        float d = acc[0][r] * adv[0] + acc[1][r] * adv[1];
#pragma unroll
        for (int o = 1; o < 16; o <<= 1) { s += __shfl_xor(s, o); d += __shfl_xor(d, o); }
        if (l15 == 0 && row < N) {
            atomicAdd(&a_s2[row], s);
            atomicAdd(&a_d2[row], d);
        }
    }
}

// ============ Layer 2 fused softmax+aggregate + b2 -> out ============
// 8 dsts/block (4 waves x two 32-lane halves), no barriers, 16-deep ILP.
__global__ __launch_bounds__(256) void k_agg2_fused(const int* __restrict__ rowptr,
    const int* __restrict__ csr_src, const float* __restrict__ a_s2,
    const float* __restrict__ a_d2, const __hip_bfloat16* __restrict__ h3b,
    const float* __restrict__ b2, float* __restrict__ out, int N)
{
    const int tt = threadIdx.x, wv = tt >> 6, t = tt & 63;
    const int half = t >> 5, l = t & 31;
    const int dst = blockIdx.x * 8 + wv * 2 + half;
    const bool valid = dst < N;
    __shared__ int   s_off[4][2][32];
    __shared__ float s_ex[4][2][32];
    int start = 0, end = 0;
    float adv = 0.f;
    if (valid) { start = rowptr[dst]; end = rowptr[dst + 1]; adv = a_d2[dst]; }
    int trips = (end - start + 31) >> 5;
#pragma unroll
    for (int o = 32; o > 0; o >>= 1) { int u = __shfl_xor(trips, o); trips = u > trips ? u : trips; }
    const char* hbase = (const char*)h3b;
    float den = 0.f, acc0 = 0.f, acc1 = 0.f;

    for (int it = 0; it < trips; ++it) {
        int base = start + it * 32;
        int nloc = end - base; if (nloc > 32) nloc = 32; if (nloc < 0) nloc = 0;
        if (l < nloc) {
            int src = csr_src[base + l];
            s_off[wv][half][l] = src << 7;               // byte offset src*128
            float e = a_s2[src] + adv;
            e = e > 0.f ? e : NEG_SLOPE * e;
            float ex = __expf(e);
            s_ex[wv][half][l] = ex;
            den += ex;
        }
        int j = 0;
        for (; j + 15 < nloc; j += 16) {
            unsigned v[16];
#pragma unroll
            for (int q = 0; q < 16; ++q)
                v[q] = *(const unsigned*)(hbase + (size_t)(unsigned)s_off[wv][half][j + q] + l * 4);
#pragma unroll
            for (int q = 0; q < 16; ++q) {
                float e = s_ex[wv][half][j + q];
                acc0 += e * bflo(v[q]); acc1 += e * bfhi(v[q]);
            }
        }
        for (; j + 7 < nloc; j += 8) {
            unsigned v[8];
#pragma unroll
            for (int q = 0; q < 8; ++q)
                v[q] = *(const unsigned*)(hbase + (size_t)(unsigned)s_off[wv][half][j + q] + l * 4);
#pragma unroll
            for (int q = 0; q < 8; ++q) {
                float e = s_ex[wv][half][j + q];
                acc0 += e * bflo(v[q]); acc1 += e * bfhi(v[q]);
            }
        }
        for (; j < nloc; ++j) {
            unsigned v = *(const unsigned*)(hbase + (size_t)(unsigned)s_off[wv][half][j] + l * 4);
            float e = s_ex[wv][half][j];
            acc0 += e * bflo(v); acc1 += e * bfhi(v);
        }
    }
#pragma unroll
    for (int o = 16; o > 0; o >>= 1) den += __shfl_xor(den, o);
    if (valid) {
        float inv = 1.0f / den;
        float2 bb = ((const float2*)b2)[l];
        float2 ov; ov.x = acc0 * inv + bb.x; ov.y = acc1 * inv + bb.y;
        ((float2*)(out + (size_t)dst * 64))[l] = ov;
    }
}

extern "C" void kernel_launch(void* const* d_in, const int* in_sizes, int n_in,
                              void* d_out, int out_size, void* d_ws, size_t ws_size,
                              hipStream_t stream)
{
    const float* x   = (const float*)d_in[0];
    const int*   ei  = (const int*)d_in[1];
    const float* W1  = (const float*)d_in[2];
    const float* as1 = (const float*)d_in[3];
    const float* ad1 = (const float*)d_in[4];
    const float* b1  = (const float*)d_in[5];
    const float* W2  = (const float*)d_in[6];
    const float* as2 = (const float*)d_in[7];
    const float* ad2 = (const float*)d_in[8];
    const float* b2  = (const float*)d_in[9];
    float* out = (float*)d_out;

    const int N = in_sizes[0] / 128;      // 50000
    const int E = in_sizes[1] / 2;        // 800000
    const int M = E + N;                  // edges + self loops
    const int NB = (N + 255) / 256;       // scan blocks (196 <= 256)
    const int Mb = (M + 255) / 256;

    // ---- workspace layout (256B-aligned) ----
    char* w = (char*)d_ws;
    size_t o = 0;
    auto alloc = [&](size_t bytes) { size_t r = o; o = (o + bytes + 255) & ~(size_t)255; return r; };
    __hip_bfloat16* h1b   = (__hip_bfloat16*)(w + alloc((size_t)N * 256 * 2)); // 25.6 MB
    float* a_s1           = (float*)(w + alloc((size_t)N * 4 * 4));
    float* a_d1           = (float*)(w + alloc((size_t)N * 4 * 4));
    __hip_bfloat16* h2b   = (__hip_bfloat16*)(w + alloc((size_t)N * 256 * 2)); // 25.6 MB
    __hip_bfloat16* h3b   = (__hip_bfloat16*)(w + alloc((size_t)N * 64 * 2));  // 6.4 MB
    // zero-block: a_s2 | a_d2 | deg | cnt — one memset covers the span
    size_t z0 = o;
    float* a_s2           = (float*)(w + alloc((size_t)N * 4));
    float* a_d2           = (float*)(w + alloc((size_t)N * 4));
    int* deg              = (int*)(w + alloc((size_t)N * 4));
    int* cnt              = (int*)(w + alloc((size_t)N * 4));
    size_t z1 = o;
    int* rowptr           = (int*)(w + alloc((size_t)(N + 1) * 4));
    int* excl             = (int*)(w + alloc((size_t)N * 4));
    int* bsum             = (int*)(w + alloc((size_t)NB * 4));
    int* csr_src          = (int*)(w + alloc((size_t)M * 4));                  // 3.4 MB
    __hip_bfloat16* W1t   = (__hip_bfloat16*)(w + alloc((size_t)256 * KP * 2));
    __hip_bfloat16* W2t   = (__hip_bfloat16*)(w + alloc((size_t)64 * KP2 * 2));

    // ---- zero + init (hist + weight prep fused) ----
    hipMemsetAsync(w + z0, 0, z1 - z0, stream);
    const int Pb = (256 * KP + 64 * KP2 + 255) / 256;
    k_init<<<Mb + Pb, 256, 0, stream>>>(ei, E, M, deg, W1, W2, W1t, W2t, Mb);

    // ---- gemm1 (+ piggybacked scan1: deg is complete, gemm1 is independent) ----
    const int G1x = (N + 63) / 64;
    k_gemm1_mfma<<<dim3(G1x + (NB + 1) / 2, 2), 256, 0, stream>>>(
        x, W1t, as1, ad1, h1b, a_s1, a_d1, N, deg, excl, bsum, NB, G1x);

    // ---- CSR offsets + scatter ----
    k_scan23<<<NB, 256, 0, stream>>>(bsum, NB, excl, N, M, rowptr);
    k_scatter<<<Mb, 256, 0, stream>>>(ei, E, M, rowptr, cnt, csr_src);

    // ---- layer 1 aggregate ----
    k_agg1_fused<<<N, 64, 0, stream>>>(rowptr, csr_src, a_s1, a_d1, h1b, b1, h2b);

    // ---- layer 2 ----
    k_gemm2_mfma<<<(N + 31) / 32, 256, 0, stream>>>(h2b, W2t, as2, ad2, h3b, a_s2, a_d2, N);
    k_agg2_fused<<<(N + 7) / 8, 256, 0, stream>>>(rowptr, csr_src, a_s2, a_d2, h3b, b2, out, N);
}

// Round 13
// 269.155 us; speedup vs baseline: 1.1364x; 1.1216x over previous
//
#include <hip/hip_runtime.h>
#include <hip/hip_bf16.h>

#define NEG_SLOPE 0.2f

typedef __attribute__((ext_vector_type(8))) short short8;   // 8 bf16 (4 VGPRs)
typedef __attribute__((ext_vector_type(4))) float f32x4;    // MFMA accumulator

__device__ __forceinline__ float bflo(unsigned u) { return __uint_as_float(u << 16); }
__device__ __forceinline__ float bfhi(unsigned u) { return __uint_as_float(u & 0xffff0000u); }
__device__ __forceinline__ unsigned pk2bf(float a, float b) {
    __hip_bfloat162 t; t.x = __float2bfloat16(a); t.y = __float2bfloat16(b);
    return *reinterpret_cast<unsigned*>(&t);
}

#define KP  136   // padded k-stride for gemm1 tiles (128+8)
#define KP2 264   // padded k-stride for gemm2 tiles (256+8)

// ============ init: edge hist + rank (blocks [0,Eb)) + weight prep (rest) ============
// rank[i] = this edge's arrival order at its dst (reuses the hist atomic).
__global__ void k_init(const int* __restrict__ ei, int E, int* __restrict__ deg,
    int* __restrict__ rank, const float* __restrict__ W1, const float* __restrict__ W2,
    __hip_bfloat16* __restrict__ W1t, __hip_bfloat16* __restrict__ W2t, int Eb)
{
    int b = blockIdx.x;
    if (b < Eb) {
        int i = b * 256 + threadIdx.x;
        if (i < E) {
            int dst = ei[E + i];
            rank[i] = atomicAdd(&deg[dst], 1);
        }
    } else {
        int i = (b - Eb) * 256 + threadIdx.x;
        if (i < 256 * KP) {
            int n = i / KP, k = i % KP;
            W1t[i] = __float2bfloat16(k < 128 ? W1[k * 256 + n] : 0.f);
        } else {
            int j = i - 256 * KP;
            if (j < 64 * KP2) {
                int n = j / KP2, k = j % KP2;
                W2t[j] = __float2bfloat16(k < 256 ? W2[k * 64 + n] : 0.f);
            }
        }
    }
}

// ============ scan1: per-256-block inclusive scan of (deg+1) -> excl + bsum ============
// +1 = implicit self-loop at slot 0 of every row.
__global__ __launch_bounds__(256) void k_scan1(const int* __restrict__ deg, int N,
    int* __restrict__ excl, int* __restrict__ bsum)
{
    __shared__ int s[256];
    int t = threadIdx.x, i = blockIdx.x * 256 + t;
    int v = (i < N) ? deg[i] + 1 : 0;
    s[t] = v; __syncthreads();
#pragma unroll
    for (int o = 1; o < 256; o <<= 1) {
        int x = (t >= o) ? s[t - o] : 0;
        __syncthreads();
        s[t] += x;
        __syncthreads();
    }
    if (i < N) excl[i] = s[t] - v;
    if (t == 255) bsum[blockIdx.x] = s[255];
}

// ============ scatter: atomic-free (rank precomputed); self-loop at slot 0 ============
__global__ void k_scatter(const int* __restrict__ ei, const int* __restrict__ rank,
    int E, int N, const int* __restrict__ rowptr, int* __restrict__ csr_src)
{
    int i = blockIdx.x * blockDim.x + threadIdx.x;
    if (i < E) {
        int src = ei[i], dst = ei[E + i];
        csr_src[rowptr[dst] + 1 + rank[i]] = src;
    } else if (i < E + N) {
        int n = i - E;
        csr_src[rowptr[n]] = n;
    }
}

// ============ Layer 1 GEMM via MFMA + fused att dots + piggybacked scan23 ============
// Block: 64 rows x 128 cols (blockIdx.y = col half -> heads {2y, 2y+1}).
// Blocks with blockIdx.x >= G1x run scan23 (needs only scan1's output).
__global__ __launch_bounds__(256) void k_gemm1_mfma(
    const float* __restrict__ x, const __hip_bfloat16* __restrict__ W1t,
    const float* __restrict__ as1, const float* __restrict__ ad1,
    __hip_bfloat16* __restrict__ h1b, float* __restrict__ a_s1, float* __restrict__ a_d1,
    int N, int M, const int* __restrict__ excl, const int* __restrict__ bsum,
    int* __restrict__ rowptr, int NB, int G1x)
{
    __shared__ short sA[64 * KP];
    __shared__ short sB[128 * KP];

    if (blockIdx.x >= G1x) {
        // ---- scan23 block: redundant scan of bsum, write rowptr chunk ----
        int sb = (blockIdx.x - G1x) * 2 + blockIdx.y;
        if (sb >= NB) return;
        int* s = (int*)sA;
        int t = threadIdx.x;
        s[t] = (t < NB) ? bsum[t] : 0;
        __syncthreads();
#pragma unroll
        for (int o = 1; o < 256; o <<= 1) {
            int y = (t >= o) ? s[t - o] : 0;
            __syncthreads();
            s[t] += y;
            __syncthreads();
        }
        int off = (sb == 0) ? 0 : s[sb - 1];
        int i = sb * 256 + t;
        if (i < N) rowptr[i] = excl[i] + off;
        if (i == 0) rowptr[N] = M;
        return;
    }

    const int n0 = blockIdx.x * 64;
    const int c0 = blockIdx.y * 128;
    const int t = threadIdx.x, wv = t >> 6, lane = t & 63;
    const int l15 = lane & 15, q = lane >> 4;

    {
        const float4* x4 = (const float4*)x;
        for (int i = t; i < 2048; i += 256) {
            int row = i >> 5, kq = i & 31;
            float4 v = make_float4(0.f, 0.f, 0.f, 0.f);
            if (n0 + row < N) v = x4[(size_t)(n0 + row) * 32 + kq];
            uint2 p; p.x = pk2bf(v.x, v.y); p.y = pk2bf(v.z, v.w);
            *(uint2*)(sA + row * KP + kq * 4) = p;
        }
    }
    {
        const uint4* src = (const uint4*)((const short*)W1t + (size_t)c0 * KP);
        uint4* dst = (uint4*)sB;
        for (int i = t; i < (128 * KP * 2) / 16; i += 256) dst[i] = src[i];
    }
    __syncthreads();

    short8 af[4];
#pragma unroll
    for (int kc = 0; kc < 4; ++kc)
        af[kc] = *(const short8*)(sA + (wv * 16 + l15) * KP + kc * 32 + q * 8);

    f32x4 acc[8];
#pragma unroll
    for (int nt = 0; nt < 8; ++nt) {
        f32x4 a = {0.f, 0.f, 0.f, 0.f};
#pragma unroll
        for (int kc = 0; kc < 4; ++kc) {
            short8 bf = *(const short8*)(sB + (nt * 16 + l15) * KP + kc * 32 + q * 8);
            a = __builtin_amdgcn_mfma_f32_16x16x32_bf16(af[kc], bf, a, 0, 0, 0);
        }
        acc[nt] = a;
    }

    // epilogue: direct stores (LDS-transpose variant measured slower in r10)
#pragma unroll
    for (int nt = 0; nt < 8; ++nt) {
#pragma unroll
        for (int r = 0; r < 4; ++r) {
            int row = n0 + wv * 16 + q * 4 + r;
            if (row < N)
                h1b[(size_t)row * 256 + c0 + nt * 16 + l15] = __float2bfloat16(acc[nt][r]);
        }
    }

    // fused attention dots for heads {2y, 2y+1}
    float asv[8], adv[8];
#pragma unroll
    for (int nt = 0; nt < 8; ++nt) {
        asv[nt] = as1[c0 + nt * 16 + l15];
        adv[nt] = ad1[c0 + nt * 16 + l15];
    }
    const int hb = blockIdx.y * 2;
#pragma unroll
    for (int r = 0; r < 4; ++r) {
        float slo = 0.f, shi = 0.f, dlo = 0.f, dhi = 0.f;
#pragma unroll
        for (int nt = 0; nt < 4; ++nt) { slo += acc[nt][r] * asv[nt]; dlo += acc[nt][r] * adv[nt]; }
#pragma unroll
        for (int nt = 4; nt < 8; ++nt) { shi += acc[nt][r] * asv[nt]; dhi += acc[nt][r] * adv[nt]; }
#pragma unroll
        for (int o = 1; o < 16; o <<= 1) {
            slo += __shfl_xor(slo, o); shi += __shfl_xor(shi, o);
            dlo += __shfl_xor(dlo, o); dhi += __shfl_xor(dhi, o);
        }
        int row = n0 + wv * 16 + q * 4 + r;
        if (l15 == 0 && row < N) {
            a_s1[row * 4 + hb]     = slo; a_s1[row * 4 + hb + 1] = shi;
            a_d1[row * 4 + hb]     = dlo; a_d1[row * 4 + hb + 1] = dhi;
        }
    }
}

// ============ Layer 1 fused softmax+aggregate+bias+ELU (bf16 gather) ============
// 1 wave per dst (no barriers). Lane t: cols {4t..4t+3}; head h=t>>4.
// 16 gathers in flight; byte offsets precomputed in LDS.
__global__ __launch_bounds__(64) void k_agg1_fused(const int* __restrict__ rowptr,
    const int* __restrict__ csr_src, const float* __restrict__ a_s1,
    const float* __restrict__ a_d1, const __hip_bfloat16* __restrict__ h1b,
    const float* __restrict__ b1, __hip_bfloat16* __restrict__ h2b)
{
    const int dst = blockIdx.x, t = threadIdx.x;
    const int h = t >> 4;
    const int start = rowptr[dst], end = rowptr[dst + 1];
    __shared__ int   s_off[64];
    __shared__ float s_ex[64][4];
    const char* hbase = (const char*)h1b;
    float4 ad = ((const float4*)a_d1)[dst];
    float d0 = 0.f, d1 = 0.f, d2 = 0.f, d3 = 0.f;
    float a0 = 0.f, a1 = 0.f, a2 = 0.f, a3 = 0.f;

    for (int base = start; base < end; base += 64) {
        int nloc = end - base; if (nloc > 64) nloc = 64;
        if (t < nloc) {
            int src = csr_src[base + t];
            s_off[t] = src << 9;                         // byte offset src*512
            float4 as = ((const float4*)a_s1)[src];
            float e0 = as.x + ad.x; e0 = e0 > 0.f ? e0 : NEG_SLOPE * e0;
            float e1 = as.y + ad.y; e1 = e1 > 0.f ? e1 : NEG_SLOPE * e1;
            float e2 = as.z + ad.z; e2 = e2 > 0.f ? e2 : NEG_SLOPE * e2;
            float e3 = as.w + ad.w; e3 = e3 > 0.f ? e3 : NEG_SLOPE * e3;
            float x0 = __expf(e0), x1 = __expf(e1), x2 = __expf(e2), x3 = __expf(e3);
            s_ex[t][0] = x0; s_ex[t][1] = x1; s_ex[t][2] = x2; s_ex[t][3] = x3;
            d0 += x0; d1 += x1; d2 += x2; d3 += x3;
        }
        int j = 0;
        for (; j + 15 < nloc; j += 16) {
            uint2 v[16];
#pragma unroll
            for (int q = 0; q < 16; ++q)
                v[q] = *(const uint2*)(hbase + (size_t)(unsigned)s_off[j + q] + t * 8);
#pragma unroll
            for (int q = 0; q < 16; ++q) {
                float e = s_ex[j + q][h];
                a0 += e * bflo(v[q].x); a1 += e * bfhi(v[q].x);
                a2 += e * bflo(v[q].y); a3 += e * bfhi(v[q].y);
            }
        }
        for (; j + 7 < nloc; j += 8) {
            uint2 v[8];
#pragma unroll
            for (int q = 0; q < 8; ++q)
                v[q] = *(const uint2*)(hbase + (size_t)(unsigned)s_off[j + q] + t * 8);
#pragma unroll
            for (int q = 0; q < 8; ++q) {
                float e = s_ex[j + q][h];
                a0 += e * bflo(v[q].x); a1 += e * bfhi(v[q].x);
                a2 += e * bflo(v[q].y); a3 += e * bfhi(v[q].y);
            }
        }
        for (; j < nloc; ++j) {
            uint2 v = *(const uint2*)(hbase + (size_t)(unsigned)s_off[j] + t * 8);
            float e = s_ex[j][h];
            a0 += e * bflo(v.x); a1 += e * bfhi(v.x);
            a2 += e * bflo(v.y); a3 += e * bfhi(v.y);
        }
    }
#pragma unroll
    for (int o = 32; o > 0; o >>= 1) {
        d0 += __shfl_xor(d0, o); d1 += __shfl_xor(d1, o);
        d2 += __shfl_xor(d2, o); d3 += __shfl_xor(d3, o);
    }
    float den = (h == 0) ? d0 : (h == 1) ? d1 : (h == 2) ? d2 : d3;
    float inv = 1.0f / den;
    float4 bb = ((const float4*)b1)[t];
    float v0 = a0 * inv + bb.x; v0 = v0 > 0.f ? v0 : (__expf(v0) - 1.f);
    float v1 = a1 * inv + bb.y; v1 = v1 > 0.f ? v1 : (__expf(v1) - 1.f);
    float v2 = a2 * inv + bb.z; v2 = v2 > 0.f ? v2 : (__expf(v2) - 1.f);
    float v3 = a3 * inv + bb.w; v3 = v3 > 0.f ? v3 : (__expf(v3) - 1.f);
    __hip_bfloat162 p0, p1;
    p0.x = __float2bfloat16(v0); p0.y = __float2bfloat16(v1);
    p1.x = __float2bfloat16(v2); p1.y = __float2bfloat16(v3);
    __hip_bfloat162* op = (__hip_bfloat162*)(h2b + (size_t)dst * 256);
    op[2 * t] = p0; op[2 * t + 1] = p1;
}

// ============ Layer 2 GEMM via MFMA + fused att dots (direct stores) ============
__global__ __launch_bounds__(256) void k_gemm2_mfma(
    const __hip_bfloat16* __restrict__ h2b, const __hip_bfloat16* __restrict__ W2t,
    const float* __restrict__ as2, const float* __restrict__ ad2,
    __hip_bfloat16* __restrict__ h3b, float* __restrict__ a_s2, float* __restrict__ a_d2,
    int N)
{
    const int n0 = blockIdx.x * 32;
    const int t = threadIdx.x, wv = t >> 6, lane = t & 63;
    const int l15 = lane & 15, q = lane >> 4;
    const int rs = wv & 1, ch = wv >> 1;

    __shared__ short sA[32 * KP2];
    __shared__ short sB[64 * KP2];

    {
        const uint4* src = (const uint4*)W2t;
        uint4* dst = (uint4*)sB;
        for (int i = t; i < (64 * KP2 * 2) / 16; i += 256) dst[i] = src[i];
    }
    {
        for (int i = t; i < 1024; i += 256) {
            int row = i >> 5, kq = i & 31;
            uint4 v = make_uint4(0, 0, 0, 0);
            if (n0 + row < N) v = ((const uint4*)(h2b + (size_t)(n0 + row) * 256))[kq];
            *(uint4*)(sA + row * KP2 + kq * 8) = v;
        }
    }
    __syncthreads();

    short8 af[8];
#pragma unroll
    for (int kc = 0; kc < 8; ++kc)
        af[kc] = *(const short8*)(sA + (rs * 16 + l15) * KP2 + kc * 32 + q * 8);

    f32x4 acc[2];
#pragma unroll
    for (int nt = 0; nt < 2; ++nt) {
        f32x4 a = {0.f, 0.f, 0.f, 0.f};
#pragma unroll
        for (int kc = 0; kc < 8; ++kc) {
            short8 bf = *(const short8*)(sB + (ch * 32 + nt * 16 + l15) * KP2 + kc * 32 + q * 8);
            a = __builtin_amdgcn_mfma_f32_16x16x32_bf16(af[kc], bf, a, 0, 0, 0);
        }
        acc[nt] = a;
    }

    float asv[2], adv[2];
#pragma unroll
    for (int nt = 0; nt < 2; ++nt) {
        int col = ch * 32 + nt * 16 + l15;
        asv[nt] = as2[col]; adv[nt] = ad2[col];
    }
#pragma unroll
    for (int r = 0; r < 4; ++r) {
        int row = n0 + rs * 16 + q * 4 + r;
        if (row < N) {
#pragma unroll
            for (int nt = 0; nt < 2; ++nt)
                h3b[(size_t)row * 64 + ch * 32 + nt * 16 + l15] = __float2bfloat16(acc[nt][r]);
        }
        float s = acc[0][r] * asv[0] + acc[1][r] * asv[1];
        float d = acc[0][r] * adv[0] + acc[1][r] * adv[1];
#pragma unroll
        for (int o = 1; o < 16; o <<= 1) { s += __shfl_xor(s, o); d += __shfl_xor(d, o); }
        if (l15 == 0 && row < N) {
            atomicAdd(&a_s2[row], s);
            atomicAdd(&a_d2[row], d);
        }
    }
}

// ============ Layer 2 fused softmax+aggregate + b2 -> out ============
// 8 dsts/block (4 waves x two 32-lane halves), no barriers, 16-deep ILP.
__global__ __launch_bounds__(256) void k_agg2_fused(const int* __restrict__ rowptr,
    const int* __restrict__ csr_src, const float* __restrict__ a_s2,
    const float* __restrict__ a_d2, const __hip_bfloat16* __restrict__ h3b,
    const float* __restrict__ b2, float* __restrict__ out, int N)
{
    const int tt = threadIdx.x, wv = tt >> 6, t = tt & 63;
    const int half = t >> 5, l = t & 31;
    const int dst = blockIdx.x * 8 + wv * 2 + half;
    const bool valid = dst < N;
    __shared__ int   s_off[4][2][32];
    __shared__ float s_ex[4][2][32];
    int start = 0, end = 0;
    float adv = 0.f;
    if (valid) { start = rowptr[dst]; end = rowptr[dst + 1]; adv = a_d2[dst]; }
    int trips = (end - start + 31) >> 5;
#pragma unroll
    for (int o = 32; o > 0; o >>= 1) { int u = __shfl_xor(trips, o); trips = u > trips ? u : trips; }
    const char* hbase = (const char*)h3b;
    float den = 0.f, acc0 = 0.f, acc1 = 0.f;

    for (int it = 0; it < trips; ++it) {
        int base = start + it * 32;
        int nloc = end - base; if (nloc > 32) nloc = 32; if (nloc < 0) nloc = 0;
        if (l < nloc) {
            int src = csr_src[base + l];
            s_off[wv][half][l] = src << 7;               // byte offset src*128
            float e = a_s2[src] + adv;
            e = e > 0.f ? e : NEG_SLOPE * e;
            float ex = __expf(e);
            s_ex[wv][half][l] = ex;
            den += ex;
        }
        int j = 0;
        for (; j + 15 < nloc; j += 16) {
            unsigned v[16];
#pragma unroll
            for (int q = 0; q < 16; ++q)
                v[q] = *(const unsigned*)(hbase + (size_t)(unsigned)s_off[wv][half][j + q] + l * 4);
#pragma unroll
            for (int q = 0; q < 16; ++q) {
                float e = s_ex[wv][half][j + q];
                acc0 += e * bflo(v[q]); acc1 += e * bfhi(v[q]);
            }
        }
        for (; j + 7 < nloc; j += 8) {
            unsigned v[8];
#pragma unroll
            for (int q = 0; q < 8; ++q)
                v[q] = *(const unsigned*)(hbase + (size_t)(unsigned)s_off[wv][half][j + q] + l * 4);
#pragma unroll
            for (int q = 0; q < 8; ++q) {
                float e = s_ex[wv][half][j + q];
                acc0 += e * bflo(v[q]); acc1 += e * bfhi(v[q]);
            }
        }
        for (; j < nloc; ++j) {
            unsigned v = *(const unsigned*)(hbase + (size_t)(unsigned)s_off[wv][half][j] + l * 4);
            float e = s_ex[wv][half][j];
            acc0 += e * bflo(v); acc1 += e * bfhi(v);
        }
    }
#pragma unroll
    for (int o = 16; o > 0; o >>= 1) den += __shfl_xor(den, o);
    if (valid) {
        float inv = 1.0f / den;
        float2 bb = ((const float2*)b2)[l];
        float2 ov; ov.x = acc0 * inv + bb.x; ov.y = acc1 * inv + bb.y;
        ((float2*)(out + (size_t)dst * 64))[l] = ov;
    }
}

extern "C" void kernel_launch(void* const* d_in, const int* in_sizes, int n_in,
                              void* d_out, int out_size, void* d_ws, size_t ws_size,
                              hipStream_t stream)
{
    const float* x   = (const float*)d_in[0];
    const int*   ei  = (const int*)d_in[1];
    const float* W1  = (const float*)d_in[2];
    const float* as1 = (const float*)d_in[3];
    const float* ad1 = (const float*)d_in[4];
    const float* b1  = (const float*)d_in[5];
    const float* W2  = (const float*)d_in[6];
    const float* as2 = (const float*)d_in[7];
    const float* ad2 = (const float*)d_in[8];
    const float* b2  = (const float*)d_in[9];
    float* out = (float*)d_out;

    const int N = in_sizes[0] / 128;      // 50000
    const int E = in_sizes[1] / 2;        // 800000
    const int M = E + N;                  // edges + self loops
    const int NB = (N + 255) / 256;       // scan blocks (196 <= 256)
    const int Eb = (E + 255) / 256;

    // ---- workspace layout (256B-aligned) ----
    char* w = (char*)d_ws;
    size_t o = 0;
    auto alloc = [&](size_t bytes) { size_t r = o; o = (o + bytes + 255) & ~(size_t)255; return r; };
    __hip_bfloat16* h1b   = (__hip_bfloat16*)(w + alloc((size_t)N * 256 * 2)); // 25.6 MB
    float* a_s1           = (float*)(w + alloc((size_t)N * 4 * 4));
    float* a_d1           = (float*)(w + alloc((size_t)N * 4 * 4));
    __hip_bfloat16* h2b   = (__hip_bfloat16*)(w + alloc((size_t)N * 256 * 2)); // 25.6 MB
    __hip_bfloat16* h3b   = (__hip_bfloat16*)(w + alloc((size_t)N * 64 * 2));  // 6.4 MB
    // zero-block: a_s2 | a_d2 | deg — one memset covers the span
    size_t z0 = o;
    float* a_s2           = (float*)(w + alloc((size_t)N * 4));
    float* a_d2           = (float*)(w + alloc((size_t)N * 4));
    int* deg              = (int*)(w + alloc((size_t)N * 4));
    size_t z1 = o;
    int* rank             = (int*)(w + alloc((size_t)E * 4));                  // 3.2 MB
    int* rowptr           = (int*)(w + alloc((size_t)(N + 1) * 4));
    int* excl             = (int*)(w + alloc((size_t)N * 4));
    int* bsum             = (int*)(w + alloc((size_t)NB * 4));
    int* csr_src          = (int*)(w + alloc((size_t)M * 4));                  // 3.4 MB
    __hip_bfloat16* W1t   = (__hip_bfloat16*)(w + alloc((size_t)256 * KP * 2));
    __hip_bfloat16* W2t   = (__hip_bfloat16*)(w + alloc((size_t)64 * KP2 * 2));

    // ---- zero + init (edge hist/rank + weight prep fused) ----
    hipMemsetAsync(w + z0, 0, z1 - z0, stream);
    const int Pb = (256 * KP + 64 * KP2 + 255) / 256;
    k_init<<<Eb + Pb, 256, 0, stream>>>(ei, E, deg, rank, W1, W2, W1t, W2t, Eb);

    // ---- scan1 (tiny), then gemm1 (+ piggybacked scan23) ----
    k_scan1<<<NB, 256, 0, stream>>>(deg, N, excl, bsum);
    const int G1x = (N + 63) / 64;
    k_gemm1_mfma<<<dim3(G1x + (NB + 1) / 2, 2), 256, 0, stream>>>(
        x, W1t, as1, ad1, h1b, a_s1, a_d1, N, M, excl, bsum, rowptr, NB, G1x);

    // ---- scatter (atomic-free) ----
    k_scatter<<<(M + 255) / 256, 256, 0, stream>>>(ei, rank, E, N, rowptr, csr_src);

    // ---- layer 1 aggregate ----
    k_agg1_fused<<<N, 64, 0, stream>>>(rowptr, csr_src, a_s1, a_d1, h1b, b1, h2b);

    // ---- layer 2 ----
    k_gemm2_mfma<<<(N + 31) / 32, 256, 0, stream>>>(h2b, W2t, as2, ad2, h3b, a_s2, a_d2, N);
    k_agg2_fused<<<(N + 7) / 8, 256, 0, stream>>>(rowptr, csr_src, a_s2, a_d2, h3b, b2, out, N);
}